// Round 1
// baseline (1230.931 us; speedup 1.0000x reference)
//
#include <hip/hip_runtime.h>

// Problem constants (match reference)
#define D_IN   64
#define D_OUT  64

// ---------------------------------------------------------------------------
// Kernel 1: edge scatter.  16 threads per edge, each handles a float4 chunk
// of the 64-float feature row.  feat row = 256 B contiguous -> the 16 lanes
// of one edge issue one coalesced 256 B gather.  atomicAdd f32 (fire and
// forget, global_atomic_add_f32) into neigh_sum; lane c==0 bumps degree.
// ---------------------------------------------------------------------------
__global__ __launch_bounds__(256) void sage_scatter(
    const float* __restrict__ feat, const int* __restrict__ src,
    const int* __restrict__ dst, const float* __restrict__ ew,
    const float* __restrict__ em, float* __restrict__ neigh,
    float* __restrict__ deg, int E) {
  int tid = blockIdx.x * blockDim.x + threadIdx.x;
  int e = tid >> 4;
  if (e >= E) return;
  int c = tid & 15;

  int s = src[e];
  int d = dst[e];
  float w = ew[e] * em[e];

  float4 f = reinterpret_cast<const float4*>(feat)[(size_t)s * 16 + c];
  float* base = neigh + (size_t)d * D_IN + c * 4;
  atomicAdd(base + 0, f.x * w);
  atomicAdd(base + 1, f.y * w);
  atomicAdd(base + 2, f.z * w);
  atomicAdd(base + 3, f.w * w);
  if (c == 0) atomicAdd(deg + d, 1.0f);
}

// ---------------------------------------------------------------------------
// Kernel 2: fused  out = feat @ Ws^T + bs + (neigh/deg) @ Wn^T + bn
// Treated as A[64nodes x 128] @ B[128 x 64] per block.
// LDS: As[k][n] (k-major, 32 KB) + Bs[k][j] (32 KB) = 64 KB.
// 256 threads, each computes a 4x4 micro-tile via two ds_read_b128 per k.
// ---------------------------------------------------------------------------
__global__ __launch_bounds__(256) void sage_fuse_gemm(
    const float* __restrict__ feat, const float* __restrict__ neigh,
    const float* __restrict__ deg, const float* __restrict__ Ws,
    const float* __restrict__ bs, const float* __restrict__ Wn,
    const float* __restrict__ bn, float* __restrict__ out, int N) {
  __shared__ float As[128][64];  // [k][node] ; k<64: feat, k>=64: h_neigh
  __shared__ float Bs[128][64];  // [k][out_j]

  const int t = threadIdx.x;
  const int n0 = blockIdx.x * 64;

  // Stage B: W[j][k] (row-major) -> Bs[k][j]  (once per block; write
  // conflicts amortized over the 128-deep k loop)
  for (int i = t; i < 4096; i += 256) {
    int j = i >> 6, k = i & 63;
    Bs[k][j] = Ws[i];
    Bs[k + 64][j] = Wn[i];
  }

  // Stage A (feat part): coalesced float4 global reads, transposed LDS write
  for (int i = t; i < 1024; i += 256) {
    int n = i >> 4;   // local node 0..63
    int c = i & 15;   // float4 column
    int gn = n0 + n;
    float4 v = make_float4(0.f, 0.f, 0.f, 0.f);
    if (gn < N) v = reinterpret_cast<const float4*>(feat)[(size_t)gn * 16 + c];
    As[c * 4 + 0][n] = v.x;
    As[c * 4 + 1][n] = v.y;
    As[c * 4 + 2][n] = v.z;
    As[c * 4 + 3][n] = v.w;
  }
  // Stage A (h_neigh part): divide by degree while staging
  for (int i = t; i < 1024; i += 256) {
    int n = i >> 4;
    int c = i & 15;
    int gn = n0 + n;
    float4 v = make_float4(0.f, 0.f, 0.f, 0.f);
    float inv = 0.f;
    if (gn < N) {
      v = reinterpret_cast<const float4*>(neigh)[(size_t)gn * 16 + c];
      inv = 1.0f / fmaxf(deg[gn], 1.0f);
    }
    As[64 + c * 4 + 0][n] = v.x * inv;
    As[64 + c * 4 + 1][n] = v.y * inv;
    As[64 + c * 4 + 2][n] = v.z * inv;
    As[64 + c * 4 + 3][n] = v.w * inv;
  }
  __syncthreads();

  const int tx = t & 15;  // output-feature group (j = tx*4 .. tx*4+3)
  const int ty = t >> 4;  // node group         (n = ty*4 .. ty*4+3)

  float acc[4][4];
  {
    float b0 = bs[tx * 4 + 0] + bn[tx * 4 + 0];
    float b1 = bs[tx * 4 + 1] + bn[tx * 4 + 1];
    float b2 = bs[tx * 4 + 2] + bn[tx * 4 + 2];
    float b3 = bs[tx * 4 + 3] + bn[tx * 4 + 3];
    for (int i = 0; i < 4; ++i) {
      acc[i][0] = b0; acc[i][1] = b1; acc[i][2] = b2; acc[i][3] = b3;
    }
  }

#pragma unroll 8
  for (int k = 0; k < 128; ++k) {
    float4 a = *reinterpret_cast<const float4*>(&As[k][ty * 4]);
    float4 b = *reinterpret_cast<const float4*>(&Bs[k][tx * 4]);
    acc[0][0] += a.x * b.x; acc[0][1] += a.x * b.y;
    acc[0][2] += a.x * b.z; acc[0][3] += a.x * b.w;
    acc[1][0] += a.y * b.x; acc[1][1] += a.y * b.y;
    acc[1][2] += a.y * b.z; acc[1][3] += a.y * b.w;
    acc[2][0] += a.z * b.x; acc[2][1] += a.z * b.y;
    acc[2][2] += a.z * b.z; acc[2][3] += a.z * b.w;
    acc[3][0] += a.w * b.x; acc[3][1] += a.w * b.y;
    acc[3][2] += a.w * b.z; acc[3][3] += a.w * b.w;
  }

  for (int i = 0; i < 4; ++i) {
    int gn = n0 + ty * 4 + i;
    if (gn < N) {
      float4 v = make_float4(acc[i][0], acc[i][1], acc[i][2], acc[i][3]);
      reinterpret_cast<float4*>(out)[(size_t)gn * 16 + tx] = v;
    }
  }
}

extern "C" void kernel_launch(void* const* d_in, const int* in_sizes, int n_in,
                              void* d_out, int out_size, void* d_ws, size_t ws_size,
                              hipStream_t stream) {
  const float* feat = (const float*)d_in[0];
  const int*   src  = (const int*)d_in[1];
  const int*   dst  = (const int*)d_in[2];
  const float* ew   = (const float*)d_in[3];
  const float* em   = (const float*)d_in[4];
  const float* Ws   = (const float*)d_in[5];
  const float* bs   = (const float*)d_in[6];
  const float* Wn   = (const float*)d_in[7];
  const float* bn   = (const float*)d_in[8];
  float* out = (float*)d_out;

  const int N = in_sizes[0] / D_IN;   // 100000
  const int E = in_sizes[1];          // 1200000

  // Workspace layout: neigh_sum [N*64] floats, deg [N] floats
  float* neigh = (float*)d_ws;
  float* deg   = neigh + (size_t)N * D_IN;

  // Zero accumulators (ws is re-poisoned to 0xAA before every launch)
  hipMemsetAsync(d_ws, 0, (size_t)N * (D_IN + 1) * sizeof(float), stream);

  // Scatter: 16 threads per edge
  {
    long long threads = (long long)E * 16;
    int block = 256;
    int grid = (int)((threads + block - 1) / block);
    sage_scatter<<<grid, block, 0, stream>>>(feat, src, dst, ew, em, neigh, deg, E);
  }

  // Fused mean-normalize + dual linear
  {
    int grid = (N + 63) / 64;
    sage_fuse_gemm<<<grid, 256, 0, stream>>>(feat, neigh, deg, Ws, bs, Wn, bn, out, N);
  }
}

// Round 2
// 344.184 us; speedup vs baseline: 3.5764x; 3.5764x over previous
//
#include <hip/hip_runtime.h>

#define D_IN   64
#define D_OUT  64

#define SCAN_TPB 256
#define SCAN_EPT 8
#define SCAN_TILE (SCAN_TPB * SCAN_EPT)  // 2048

// ---------------------------------------------------------------------------
// CSR build, pass 1: degree count (int atomics, 1.2M ops over 100k addrs)
// ---------------------------------------------------------------------------
__global__ __launch_bounds__(256) void k_count(const int* __restrict__ dst,
                                               int* __restrict__ cnt, int E) {
  int e = blockIdx.x * blockDim.x + threadIdx.x;
  if (e < E) atomicAdd(&cnt[dst[e]], 1);
}

// ---------------------------------------------------------------------------
// Hierarchical exclusive scan of cnt[N] -> row_ptr[N]  (3 kernels)
// ---------------------------------------------------------------------------
__global__ __launch_bounds__(SCAN_TPB) void k_scan1(
    const int* __restrict__ cnt, int* __restrict__ excl,
    int* __restrict__ partials, int N) {
  __shared__ int s[SCAN_TPB];
  int b = blockIdx.x, t = threadIdx.x;
  int base = b * SCAN_TILE + t * SCAN_EPT;
  int v[SCAN_EPT];
  int sum = 0;
#pragma unroll
  for (int i = 0; i < SCAN_EPT; ++i) {
    int idx = base + i;
    v[i] = (idx < N) ? cnt[idx] : 0;
    sum += v[i];
  }
  s[t] = sum;
  __syncthreads();
  // Hillis-Steele inclusive scan over thread sums
  for (int off = 1; off < SCAN_TPB; off <<= 1) {
    int x = (t >= off) ? s[t - off] : 0;
    __syncthreads();
    s[t] += x;
    __syncthreads();
  }
  if (t == SCAN_TPB - 1) partials[b] = s[t];
  int run = (t == 0) ? 0 : s[t - 1];
#pragma unroll
  for (int i = 0; i < SCAN_EPT; ++i) {
    int idx = base + i;
    if (idx < N) excl[idx] = run;
    run += v[i];
  }
}

__global__ __launch_bounds__(256) void k_scan2(int* __restrict__ partials, int P) {
  __shared__ int s[256];
  int t = threadIdx.x;
  s[t] = (t < P) ? partials[t] : 0;
  __syncthreads();
  for (int off = 1; off < 256; off <<= 1) {
    int x = (t >= off) ? s[t - off] : 0;
    __syncthreads();
    s[t] += x;
    __syncthreads();
  }
  if (t < P) partials[t] = (t == 0) ? 0 : s[t - 1];  // exclusive
}

__global__ __launch_bounds__(256) void k_scan3(
    int* __restrict__ excl, const int* __restrict__ partials,
    int* __restrict__ cursor, int N) {
  int n = blockIdx.x * blockDim.x + threadIdx.x;
  if (n < N) {
    int v = excl[n] + partials[n / SCAN_TILE];
    excl[n] = v;    // becomes row_ptr
    cursor[n] = v;  // fill cursor starts at row_ptr
  }
}

// ---------------------------------------------------------------------------
// CSR build, pass 2: scatter (src, w) into dst-buckets
// ---------------------------------------------------------------------------
__global__ __launch_bounds__(256) void k_fill(
    const int* __restrict__ src, const int* __restrict__ dst,
    const float* __restrict__ ew, const float* __restrict__ em,
    int* __restrict__ cursor, int* __restrict__ e_src,
    float* __restrict__ e_w, int E) {
  int e = blockIdx.x * blockDim.x + threadIdx.x;
  if (e >= E) return;
  int d = dst[e];
  int p = atomicAdd(&cursor[d], 1);
  e_src[p] = src[e];
  e_w[p] = ew[e] * em[e];
}

// ---------------------------------------------------------------------------
// Fused: per-64-node block
//   phase 1: stage weights (Bs) + feat rows (As[0:64])
//   phase 2: gather-reduce each node's edge bucket from L2/L3-resident feat,
//            mean-normalize, deposit h_neigh into As[64:128]  (no HBM trip)
//   phase 3: out = A[64x128] @ B[128x64] + (bs+bn), 4x4 register micro-tile
// ---------------------------------------------------------------------------
__global__ __launch_bounds__(256) void sage_fused(
    const float* __restrict__ feat, const int* __restrict__ row_ptr,
    const int* __restrict__ cnt, const int* __restrict__ e_src,
    const float* __restrict__ e_w, const float* __restrict__ Ws,
    const float* __restrict__ bs, const float* __restrict__ Wn,
    const float* __restrict__ bn, float* __restrict__ out, int N) {
  __shared__ float As[128][64];  // [k][node]; k<64: feat, k>=64: h_neigh
  __shared__ float Bs[128][64];  // [k][out_j]

  const int t = threadIdx.x;
  const int n0 = blockIdx.x * 64;

  // Stage B: W[j][k] row-major -> Bs[k][j]
  for (int i = t; i < 4096; i += 256) {
    int j = i >> 6, k = i & 63;
    Bs[k][j] = Ws[i];
    Bs[k + 64][j] = Wn[i];
  }

  // Stage A (feat): coalesced float4 reads, transposed LDS writes
  for (int i = t; i < 1024; i += 256) {
    int n = i >> 4;
    int c = i & 15;
    int gn = n0 + n;
    float4 v = make_float4(0.f, 0.f, 0.f, 0.f);
    if (gn < N) v = reinterpret_cast<const float4*>(feat)[(size_t)gn * 16 + c];
    As[c * 4 + 0][n] = v.x;
    As[c * 4 + 1][n] = v.y;
    As[c * 4 + 2][n] = v.z;
    As[c * 4 + 3][n] = v.w;
  }

  // Gather phase: 4 threads per node; thread q covers float4 cols q*4..q*4+3
  {
    int nl = t >> 2;       // local node 0..63
    int q  = t & 3;        // quarter of the 64-float row
    int gn = n0 + nl;
    float4 acc[4];
#pragma unroll
    for (int i = 0; i < 4; ++i) acc[i] = make_float4(0.f, 0.f, 0.f, 0.f);
    if (gn < N) {
      int beg = row_ptr[gn];
      int d = cnt[gn];
      for (int j = 0; j < d; ++j) {
        int s = e_src[beg + j];          // broadcast across the 4 lanes
        float w = e_w[beg + j];
        const float4* fr = reinterpret_cast<const float4*>(feat) + (size_t)s * 16 + q * 4;
#pragma unroll
        for (int i = 0; i < 4; ++i) {
          float4 f = fr[i];
          acc[i].x += w * f.x; acc[i].y += w * f.y;
          acc[i].z += w * f.z; acc[i].w += w * f.w;
        }
      }
      float inv = 1.0f / fmaxf((float)d, 1.0f);
#pragma unroll
      for (int i = 0; i < 4; ++i) {
        int c = q * 4 + i;  // float4 col
        As[64 + c * 4 + 0][nl] = acc[i].x * inv;
        As[64 + c * 4 + 1][nl] = acc[i].y * inv;
        As[64 + c * 4 + 2][nl] = acc[i].z * inv;
        As[64 + c * 4 + 3][nl] = acc[i].w * inv;
      }
    } else {
#pragma unroll
      for (int i = 0; i < 4; ++i) {
        int c = q * 4 + i;
        As[64 + c * 4 + 0][nl] = 0.f;
        As[64 + c * 4 + 1][nl] = 0.f;
        As[64 + c * 4 + 2][nl] = 0.f;
        As[64 + c * 4 + 3][nl] = 0.f;
      }
    }
  }
  __syncthreads();

  const int tx = t & 15;  // output-feature group (j = tx*4..)
  const int ty = t >> 4;  // node group          (n = ty*4..)

  float acc[4][4];
  {
    float b0 = bs[tx * 4 + 0] + bn[tx * 4 + 0];
    float b1 = bs[tx * 4 + 1] + bn[tx * 4 + 1];
    float b2 = bs[tx * 4 + 2] + bn[tx * 4 + 2];
    float b3 = bs[tx * 4 + 3] + bn[tx * 4 + 3];
    for (int i = 0; i < 4; ++i) {
      acc[i][0] = b0; acc[i][1] = b1; acc[i][2] = b2; acc[i][3] = b3;
    }
  }

#pragma unroll 8
  for (int k = 0; k < 128; ++k) {
    float4 a = *reinterpret_cast<const float4*>(&As[k][ty * 4]);
    float4 b = *reinterpret_cast<const float4*>(&Bs[k][tx * 4]);
    acc[0][0] += a.x * b.x; acc[0][1] += a.x * b.y;
    acc[0][2] += a.x * b.z; acc[0][3] += a.x * b.w;
    acc[1][0] += a.y * b.x; acc[1][1] += a.y * b.y;
    acc[1][2] += a.y * b.z; acc[1][3] += a.y * b.w;
    acc[2][0] += a.z * b.x; acc[2][1] += a.z * b.y;
    acc[2][2] += a.z * b.z; acc[2][3] += a.z * b.w;
    acc[3][0] += a.w * b.x; acc[3][1] += a.w * b.y;
    acc[3][2] += a.w * b.z; acc[3][3] += a.w * b.w;
  }

  for (int i = 0; i < 4; ++i) {
    int gn = n0 + ty * 4 + i;
    if (gn < N) {
      float4 v = make_float4(acc[i][0], acc[i][1], acc[i][2], acc[i][3]);
      reinterpret_cast<float4*>(out)[(size_t)gn * 16 + tx] = v;
    }
  }
}

extern "C" void kernel_launch(void* const* d_in, const int* in_sizes, int n_in,
                              void* d_out, int out_size, void* d_ws, size_t ws_size,
                              hipStream_t stream) {
  const float* feat = (const float*)d_in[0];
  const int*   src  = (const int*)d_in[1];
  const int*   dst  = (const int*)d_in[2];
  const float* ew   = (const float*)d_in[3];
  const float* em   = (const float*)d_in[4];
  const float* Ws   = (const float*)d_in[5];
  const float* bs   = (const float*)d_in[6];
  const float* Wn   = (const float*)d_in[7];
  const float* bn   = (const float*)d_in[8];
  float* out = (float*)d_out;

  const int N = in_sizes[0] / D_IN;   // 100000
  const int E = in_sizes[1];          // 1200000

  // Workspace layout (ints/floats, all 4B): ~10.8 MB total
  int*   cnt      = (int*)d_ws;             // N
  int*   row_ptr  = cnt + N;                // N
  int*   cursor   = row_ptr + N;            // N
  int*   partials = cursor + N;             // 256
  int*   e_src    = partials + 256;         // E
  float* e_w      = (float*)(e_src + E);    // E

  hipMemsetAsync(cnt, 0, (size_t)N * sizeof(int), stream);

  int gE = (E + 255) / 256;
  int gN = (N + 255) / 256;
  int nScan = (N + SCAN_TILE - 1) / SCAN_TILE;  // 49

  k_count<<<gE, 256, 0, stream>>>(dst, cnt, E);
  k_scan1<<<nScan, SCAN_TPB, 0, stream>>>(cnt, row_ptr, partials, N);
  k_scan2<<<1, 256, 0, stream>>>(partials, nScan);
  k_scan3<<<gN, 256, 0, stream>>>(row_ptr, partials, cursor, N);
  k_fill<<<gE, 256, 0, stream>>>(src, dst, ew, em, cursor, e_src, e_w, E);

  int gF = (N + 63) / 64;
  sage_fused<<<gF, 256, 0, stream>>>(feat, row_ptr, cnt, e_src, e_w,
                                     Ws, bs, Wn, bn, out, N);
}

// Round 3
// 252.789 us; speedup vs baseline: 4.8694x; 1.3616x over previous
//
#include <hip/hip_runtime.h>

#define D_IN   64
#define D_OUT  64
#define APAD   68   // LDS row stride in floats: 68*4B=272B, 16B-aligned, banks cycle

// ---------------------------------------------------------------------------
// Build: one pass. Linked-list bucketing of edges by dst.
//   head[d] -> most recent edge id for node d (-1 = empty)
//   ll[e]   = {next_edge, src_node, bitcast(ew*em), pad}
// Only the atomicExch is scattered; ll write + all reads are coalesced.
// ---------------------------------------------------------------------------
__global__ __launch_bounds__(256) void k_link(
    const int* __restrict__ src, const int* __restrict__ dst,
    const float* __restrict__ ew, const float* __restrict__ em,
    int* __restrict__ head, int4* __restrict__ ll, int E) {
  int e = blockIdx.x * blockDim.x + threadIdx.x;
  if (e >= E) return;
  int d = dst[e];
  int old = atomicExch(&head[d], e);
  ll[e] = make_int4(old, src[e], __float_as_int(ew[e] * em[e]), 0);
}

// ---------------------------------------------------------------------------
// Fused: per-64-node block
//   phase 1: stage weights (Bs) + feat rows (As[0:64])
//   phase 2: 4 threads/node walk the node's edge chain; the 16B ll load
//            carries next+src+w, so only that load is on the serial chain.
//            feat row gathers (4 x float4 per lane) overlap the chase.
//            Mean-normalize, deposit h_neigh into As[64:128].
//   phase 3: out = A[64x128] @ B[128x64] + (bs+bn), 4x4 register micro-tile
// LDS rows padded to 68 floats: all accesses <=2-way bank aliased (free).
// ---------------------------------------------------------------------------
__global__ __launch_bounds__(256) void sage_fused(
    const float* __restrict__ feat, const int* __restrict__ head,
    const int4* __restrict__ ll, const float* __restrict__ Ws,
    const float* __restrict__ bs, const float* __restrict__ Wn,
    const float* __restrict__ bn, float* __restrict__ out, int N) {
  __shared__ float As[128][APAD];  // [k][node]; k<64: feat, k>=64: h_neigh
  __shared__ float Bs[128][APAD];  // [k][out_j]

  const int t = threadIdx.x;
  const int n0 = blockIdx.x * 64;

  // Stage B: W[j][k] row-major -> Bs[k][j]
  for (int i = t; i < 4096; i += 256) {
    int j = i >> 6, k = i & 63;
    Bs[k][j] = Ws[i];
    Bs[k + 64][j] = Wn[i];
  }

  // Stage A (feat): coalesced float4 reads, transposed LDS writes
  for (int i = t; i < 1024; i += 256) {
    int n = i >> 4;
    int c = i & 15;
    int gn = n0 + n;
    float4 v = make_float4(0.f, 0.f, 0.f, 0.f);
    if (gn < N) v = reinterpret_cast<const float4*>(feat)[(size_t)gn * 16 + c];
    As[c * 4 + 0][n] = v.x;
    As[c * 4 + 1][n] = v.y;
    As[c * 4 + 2][n] = v.z;
    As[c * 4 + 3][n] = v.w;
  }

  // Gather phase: 4 threads per node walk the chain together (ll load is a
  // same-address broadcast across the 4 lanes; feat loads differ by q).
  {
    int nl = t >> 2;       // local node 0..63
    int q  = t & 3;        // quarter of the 64-float row
    int gn = n0 + nl;
    float4 acc[4];
#pragma unroll
    for (int i = 0; i < 4; ++i) acc[i] = make_float4(0.f, 0.f, 0.f, 0.f);
    int dcount = 0;
    if (gn < N) {
      int cur = head[gn];
      while (cur >= 0) {
        int4 entry = ll[cur];          // {next, src, bits(w), pad}
        cur = entry.x;
        float w = __int_as_float(entry.z);
        const float4* fr =
            reinterpret_cast<const float4*>(feat) + (size_t)entry.y * 16 + q * 4;
        float4 f0 = fr[0], f1 = fr[1], f2 = fr[2], f3 = fr[3];
        acc[0].x += w * f0.x; acc[0].y += w * f0.y;
        acc[0].z += w * f0.z; acc[0].w += w * f0.w;
        acc[1].x += w * f1.x; acc[1].y += w * f1.y;
        acc[1].z += w * f1.z; acc[1].w += w * f1.w;
        acc[2].x += w * f2.x; acc[2].y += w * f2.y;
        acc[2].z += w * f2.z; acc[2].w += w * f2.w;
        acc[3].x += w * f3.x; acc[3].y += w * f3.y;
        acc[3].z += w * f3.z; acc[3].w += w * f3.w;
        ++dcount;
      }
      float inv = 1.0f / fmaxf((float)dcount, 1.0f);
#pragma unroll
      for (int i = 0; i < 4; ++i) {
        int c = q * 4 + i;
        As[64 + c * 4 + 0][nl] = acc[i].x * inv;
        As[64 + c * 4 + 1][nl] = acc[i].y * inv;
        As[64 + c * 4 + 2][nl] = acc[i].z * inv;
        As[64 + c * 4 + 3][nl] = acc[i].w * inv;
      }
    } else {
#pragma unroll
      for (int i = 0; i < 4; ++i) {
        int c = q * 4 + i;
        As[64 + c * 4 + 0][nl] = 0.f;
        As[64 + c * 4 + 1][nl] = 0.f;
        As[64 + c * 4 + 2][nl] = 0.f;
        As[64 + c * 4 + 3][nl] = 0.f;
      }
    }
  }
  __syncthreads();

  const int tx = t & 15;  // output-feature group (j = tx*4..)
  const int ty = t >> 4;  // node group          (n = ty*4..)

  float acc[4][4];
  {
    float b0 = bs[tx * 4 + 0] + bn[tx * 4 + 0];
    float b1 = bs[tx * 4 + 1] + bn[tx * 4 + 1];
    float b2 = bs[tx * 4 + 2] + bn[tx * 4 + 2];
    float b3 = bs[tx * 4 + 3] + bn[tx * 4 + 3];
    for (int i = 0; i < 4; ++i) {
      acc[i][0] = b0; acc[i][1] = b1; acc[i][2] = b2; acc[i][3] = b3;
    }
  }

#pragma unroll 8
  for (int k = 0; k < 128; ++k) {
    float4 a = *reinterpret_cast<const float4*>(&As[k][ty * 4]);
    float4 b = *reinterpret_cast<const float4*>(&Bs[k][tx * 4]);
    acc[0][0] += a.x * b.x; acc[0][1] += a.x * b.y;
    acc[0][2] += a.x * b.z; acc[0][3] += a.x * b.w;
    acc[1][0] += a.y * b.x; acc[1][1] += a.y * b.y;
    acc[1][2] += a.y * b.z; acc[1][3] += a.y * b.w;
    acc[2][0] += a.z * b.x; acc[2][1] += a.z * b.y;
    acc[2][2] += a.z * b.z; acc[2][3] += a.z * b.w;
    acc[3][0] += a.w * b.x; acc[3][1] += a.w * b.y;
    acc[3][2] += a.w * b.z; acc[3][3] += a.w * b.w;
  }

  for (int i = 0; i < 4; ++i) {
    int gn = n0 + ty * 4 + i;
    if (gn < N) {
      float4 v = make_float4(acc[i][0], acc[i][1], acc[i][2], acc[i][3]);
      reinterpret_cast<float4*>(out)[(size_t)gn * 16 + tx] = v;
    }
  }
}

extern "C" void kernel_launch(void* const* d_in, const int* in_sizes, int n_in,
                              void* d_out, int out_size, void* d_ws, size_t ws_size,
                              hipStream_t stream) {
  const float* feat = (const float*)d_in[0];
  const int*   src  = (const int*)d_in[1];
  const int*   dst  = (const int*)d_in[2];
  const float* ew   = (const float*)d_in[3];
  const float* em   = (const float*)d_in[4];
  const float* Ws   = (const float*)d_in[5];
  const float* bs   = (const float*)d_in[6];
  const float* Wn   = (const float*)d_in[7];
  const float* bn   = (const float*)d_in[8];
  float* out = (float*)d_out;

  const int N = in_sizes[0] / D_IN;   // 100000
  const int E = in_sizes[1];          // 1200000

  // Workspace: head [N ints] (400000 B, 16B-aligned), ll [E int4] (19.2 MB)
  int*  head = (int*)d_ws;
  int4* ll   = (int4*)(head + N);

  hipMemsetAsync(head, 0xFF, (size_t)N * sizeof(int), stream);  // head = -1

  int gE = (E + 255) / 256;
  k_link<<<gE, 256, 0, stream>>>(src, dst, ew, em, head, ll, E);

  int gF = (N + 63) / 64;
  sage_fused<<<gF, 256, 0, stream>>>(feat, head, ll, Ws, bs, Wn, bn, out, N);
}